// Round 3
// baseline (544.445 us; speedup 1.0000x reference)
//
#include <hip/hip_runtime.h>

// Problem constants (fixed by the reference setup).
#define BATCH  256
#define SEQT   2048
#define LAYERS 4
#define HID    64
#define CHUNK  8                         // timesteps per barrier phase
#define PHASES (SEQT / CHUNK + LAYERS - 1)
// P (input / projected hidden size) == 1

__device__ __forceinline__ float fast_rcp(float x) {
    return __builtin_amdgcn_rcpf(x);
}

// Clamped Pade(5,4): tanh(x) ~= x(945+105u+u^2)/(945+420u+15u^2), u=x^2.
// |err| <= 4e-4 on [-3,3]; clamped (saturating) outside. No v_exp on chain.
__device__ __forceinline__ float pade_tanh(float x) {
    x = fminf(3.0f, fmaxf(-3.0f, x));          // v_med3
    const float u   = x * x;
    const float num = x * fmaf(u, u + 105.0f, 945.0f);
    const float den = fmaf(u, fmaf(15.0f, u, 420.0f), 945.0f);
    return num * fast_rcp(den);
}

// sigmoid(g) = 0.5 + 0.5*tanh(g/2); the 1/2 on g is pre-folded into weights,
// so callers pass g/2 and we do the affine fold here.
__device__ __forceinline__ float sig_from_half(float g_half) {
    return fmaf(0.5f, pade_tanh(g_half), 0.5f);
}

// One DPP-shifted add: v += dpp_move(v). bound_ctrl=true -> invalid lanes read 0.
#define DPP_ADD(v, ctrl)                                                     \
    (v) += __int_as_float(__builtin_amdgcn_update_dpp(                       \
        0, __float_as_int(v), (ctrl), 0xF, 0xF, true))

// Full wave64 sum via DPP row reduce + row broadcasts; total lands in lane 63.
__device__ __forceinline__ float wave_sum_lane63(float v) {
    DPP_ADD(v, 0x111);   // row_shr:1
    DPP_ADD(v, 0x112);   // row_shr:2
    DPP_ADD(v, 0x114);   // row_shr:4
    DPP_ADD(v, 0x118);   // row_shr:8 -> lanes 15/31/47/63 = row sums
    DPP_ADD(v, 0x142);   // row_bcast:15
    DPP_ADD(v, 0x143);   // row_bcast:31 -> lane 63 = full sum
    return v;
}

// One block per batch element. 4 waves = 4 layers, software-pipelined across
// time in CHUNK-step phases: wave l in phase p handles t in [C*(p-l), +C).
// Inter-layer h values flow through double-buffered LDS once per phase.
// Lane k = hidden unit k; c per-lane in registers; h wave-uniform (SGPR).
__global__ __launch_bounds__(256, 1) void lstm_pipeline_kernel(
    const float* __restrict__ y,      // [B, T, 1]
    const float* __restrict__ W_ih,   // [L, 4H, 1]
    const float* __restrict__ W_hh,   // [L, 4H, 1]
    const float* __restrict__ b_ih,   // [L, 4H]
    const float* __restrict__ b_hh,   // [L, 4H]
    const float* __restrict__ W_hr,   // [L, 1, H]
    const int*  __restrict__ msl_p,   // min_seq_len scalar
    float* __restrict__ out)          // [B, T - msl, 1]
{
    const int b   = blockIdx.x;
    const int tid = threadIdx.x;
    const int l   = tid >> 6;   // layer / wave id
    const int k   = tid & 63;   // hidden unit / lane
    const int msl = *msl_p;

    __shared__ float y_lds[SEQT];                              // 8 KB
    __shared__ __align__(16) float h_buf[2][LAYERS][CHUNK];    // inter-layer h

    // Stage y[b, :] into LDS with float4 loads.
    {
        const float4* y4  = (const float4*)(y + (size_t)b * SEQT);
        float4*       yl4 = (float4*)y_lds;
        #pragma unroll
        for (int i = tid; i < SEQT / 4; i += 256) yl4[i] = y4[i];
    }

    // Loop-invariant weights. Gate order: i, f, g, o. For sigmoid gates
    // (i, f, o) fold the 1/2 of sigmoid(g)=0.5+0.5*tanh(g/2) into the weights.
    const int wbase = l * 4 * HID;
    const float wi0 = 0.5f * W_ih[wbase + 0 * HID + k];
    const float wi1 = 0.5f * W_ih[wbase + 1 * HID + k];
    const float wi2 =        W_ih[wbase + 2 * HID + k];
    const float wi3 = 0.5f * W_ih[wbase + 3 * HID + k];
    const float wh0 = 0.5f * W_hh[wbase + 0 * HID + k];
    const float wh1 = 0.5f * W_hh[wbase + 1 * HID + k];
    const float wh2 =        W_hh[wbase + 2 * HID + k];
    const float wh3 = 0.5f * W_hh[wbase + 3 * HID + k];
    const float bb0 = 0.5f * (b_ih[wbase + 0 * HID + k] + b_hh[wbase + 0 * HID + k]);
    const float bb1 = 0.5f * (b_ih[wbase + 1 * HID + k] + b_hh[wbase + 1 * HID + k]);
    const float bb2 =        (b_ih[wbase + 2 * HID + k] + b_hh[wbase + 2 * HID + k]);
    const float bb3 = 0.5f * (b_ih[wbase + 3 * HID + k] + b_hh[wbase + 3 * HID + k]);
    const float wr  = W_hr[l * HID + k];

    float h = 0.0f;   // projected hidden (wave-uniform)
    float c = 0.0f;   // cell state, per lane

    float* outb = out + (size_t)b * (SEQT - msl);

    for (int p = 0; p < PHASES; ++p) {
        __syncthreads();   // publishes previous phase's h_buf writes
        const int t0 = (p - l) * CHUNK;
        if (t0 >= 0 && t0 < SEQT) {
            // Fetch this chunk's 8 scalar inputs (wave-uniform broadcast reads).
            float4 xa, xb;
            if (l == 0) {
                xa = *(const float4*)&y_lds[t0];
                xb = *(const float4*)&y_lds[t0 + 4];
            } else {
                const float4* hb = (const float4*)&h_buf[(p - 1) & 1][l - 1][0];
                xa = hb[0];
                xb = hb[1];
            }
            const float xs[CHUNK] = {xa.x, xa.y, xa.z, xa.w,
                                     xb.x, xb.y, xb.z, xb.w};

            // Input-side gate contributions: independent of h, off the chain.
            float p0[CHUNK], p1[CHUNK], p2[CHUNK], p3[CHUNK];
            #pragma unroll
            for (int j = 0; j < CHUNK; ++j) {
                p0[j] = fmaf(xs[j], wi0, bb0);
                p1[j] = fmaf(xs[j], wi1, bb1);
                p2[j] = fmaf(xs[j], wi2, bb2);
                p3[j] = fmaf(xs[j], wi3, bb3);
            }

            #pragma unroll
            for (int j = 0; j < CHUNK; ++j) {
                // Gate pre-activations (i, f, o already pre-halved).
                const float gi = fmaf(h, wh0, p0[j]);
                const float gf = fmaf(h, wh1, p1[j]);
                const float gg = fmaf(h, wh2, p2[j]);
                const float go = fmaf(h, wh3, p3[j]);

                const float si = sig_from_half(gi);
                const float sf = sig_from_half(gf);
                const float tg = pade_tanh(gg);
                const float so = sig_from_half(go);

                c = fmaf(sf, c, si * tg);

                const float sw = so * wr;          // off the c-chain
                const float v  = pade_tanh(c) * sw;

                const float vs = wave_sum_lane63(v);   // lane 63 = sum

                if (l < LAYERS - 1) {
                    // Producer handoff straight from lane 63 (no readlane wait).
                    if (k == 63) h_buf[p & 1][l][j] = vs;
                } else {
                    const int t = t0 + j;
                    if (t >= msl && k == 63) outb[t - msl] = vs;
                }
                // Broadcast for this wave's own next step.
                h = __int_as_float(
                    __builtin_amdgcn_readlane(__float_as_int(vs), 63));
            }
        }
    }
}

extern "C" void kernel_launch(void* const* d_in, const int* in_sizes, int n_in,
                              void* d_out, int out_size, void* d_ws, size_t ws_size,
                              hipStream_t stream) {
    const float* y    = (const float*)d_in[0];
    const float* W_ih = (const float*)d_in[1];
    const float* W_hh = (const float*)d_in[2];
    const float* b_ih = (const float*)d_in[3];
    const float* b_hh = (const float*)d_in[4];
    const float* W_hr = (const float*)d_in[5];
    const int*   msl  = (const int*)d_in[6];
    float* out = (float*)d_out;

    lstm_pipeline_kernel<<<BATCH, 256, 0, stream>>>(
        y, W_ih, W_hh, b_ih, b_hh, W_hr, msl, out);
}

// Round 4
// 340.669 us; speedup vs baseline: 1.5982x; 1.5982x over previous
//
#include <hip/hip_runtime.h>

// Problem constants (fixed by the reference setup).
#define BATCH  256
#define SEQT   2048
#define LAYERS 4
#define HID    64
#define CHUNK  16                        // timesteps per barrier phase
#define PHASES (SEQT / CHUNK + LAYERS - 1)
// P (input / projected hidden size) == 1

#define LOG2E  1.4426950408889634f
#define K2     (2.0f * LOG2E)            // c is carried as C = K2 * c

__device__ __forceinline__ float fast_rcp(float x) {
    return __builtin_amdgcn_rcpf(x);
}
__device__ __forceinline__ float fast_exp2(float x) {
    return __builtin_amdgcn_exp2f(x);    // raw v_exp_f32 (2^x)
}

// One DPP-shifted add: v += dpp_move(v). bound_ctrl=true -> invalid lanes read 0.
#define DPP_ADD(v, ctrl)                                                     \
    (v) += __int_as_float(__builtin_amdgcn_update_dpp(                       \
        0, __float_as_int(v), (ctrl), 0xF, 0xF, true))

// Full wave64 sum via DPP row reduce + row broadcasts; total lands in lane 63.
__device__ __forceinline__ float wave_sum_lane63(float v) {
    DPP_ADD(v, 0x111);   // row_shr:1
    DPP_ADD(v, 0x112);   // row_shr:2
    DPP_ADD(v, 0x114);   // row_shr:4
    DPP_ADD(v, 0x118);   // row_shr:8 -> lanes 15/31/47/63 = row sums
    DPP_ADD(v, 0x142);   // row_bcast:15
    DPP_ADD(v, 0x143);   // row_bcast:31 -> lane 63 = full sum
    return v;
}

// One block per batch element. 4 waves = 4 layers, software-pipelined across
// time in CHUNK-step phases: wave l in phase p handles t in [C*(p-l), +C).
// Inter-layer h flows through double-buffered LDS once per phase. Outputs are
// buffered in LDS and flushed once at the end (keeps global stores -- and the
// vmcnt(0) barrier drain they cause -- off the per-phase critical path).
// All exp() scale factors (log2e) are pre-folded into the weights; the cell
// state is carried as C = 2*log2e*c so tanh(c) needs no on-chain scaling.
__global__ __launch_bounds__(256, 1) void lstm_pipeline_kernel(
    const float* __restrict__ y,      // [B, T, 1]
    const float* __restrict__ W_ih,   // [L, 4H, 1]
    const float* __restrict__ W_hh,   // [L, 4H, 1]
    const float* __restrict__ b_ih,   // [L, 4H]
    const float* __restrict__ b_hh,   // [L, 4H]
    const float* __restrict__ W_hr,   // [L, 1, H]
    const int*  __restrict__ msl_p,   // min_seq_len scalar
    float* __restrict__ out)          // [B, T - msl, 1]
{
    const int b   = blockIdx.x;
    const int tid = threadIdx.x;
    const int l   = tid >> 6;   // layer / wave id
    const int k   = tid & 63;   // hidden unit / lane
    const int msl = *msl_p;

    __shared__ float y_lds[SEQT];                              // 8 KB
    __shared__ float out_lds[SEQT];                            // 8 KB
    __shared__ __align__(16) float h_buf[2][LAYERS][CHUNK];    // inter-layer h

    // Stage y[b, :] into LDS with float4 loads.
    {
        const float4* y4  = (const float4*)(y + (size_t)b * SEQT);
        float4*       yl4 = (float4*)y_lds;
        #pragma unroll
        for (int i = tid; i < SEQT / 4; i += 256) yl4[i] = y4[i];
    }

    // Loop-invariant weights. Gate order: i, f, g, o.
    // Sigmoid gates (i,f,o): sigma(g) = rcp(1 + exp2(-log2e * g)) -> fold -log2e.
    // Tanh gate (g):        tanh(g) = 1 - 2*rcp(exp2(2*log2e*g)+1) -> fold 2*log2e.
    const int wbase = l * 4 * HID;
    const float wi0 = -LOG2E * W_ih[wbase + 0 * HID + k];
    const float wi1 = -LOG2E * W_ih[wbase + 1 * HID + k];
    const float wi2 =  K2    * W_ih[wbase + 2 * HID + k];
    const float wi3 = -LOG2E * W_ih[wbase + 3 * HID + k];
    const float wh0 = -LOG2E * W_hh[wbase + 0 * HID + k];
    const float wh1 = -LOG2E * W_hh[wbase + 1 * HID + k];
    const float wh2 =  K2    * W_hh[wbase + 2 * HID + k];
    const float wh3 = -LOG2E * W_hh[wbase + 3 * HID + k];
    const float bb0 = -LOG2E * (b_ih[wbase + 0 * HID + k] + b_hh[wbase + 0 * HID + k]);
    const float bb1 = -LOG2E * (b_ih[wbase + 1 * HID + k] + b_hh[wbase + 1 * HID + k]);
    const float bb2 =  K2    * (b_ih[wbase + 2 * HID + k] + b_hh[wbase + 2 * HID + k]);
    const float bb3 = -LOG2E * (b_ih[wbase + 3 * HID + k] + b_hh[wbase + 3 * HID + k]);
    const float wr  = W_hr[l * HID + k];

    float h = 0.0f;   // projected hidden (wave-uniform)
    float C = 0.0f;   // cell state, scaled: C = 2*log2e*c

    for (int p = 0; p < PHASES; ++p) {
        __syncthreads();   // publishes previous phase's h_buf writes (LDS only)
        const int t0 = (p - l) * CHUNK;
        if (t0 >= 0 && t0 < SEQT) {
            // Fetch this chunk's 16 scalar inputs (wave-uniform broadcast reads).
            float4 xv[CHUNK / 4];
            if (l == 0) {
                const float4* ys = (const float4*)&y_lds[t0];
                #pragma unroll
                for (int q = 0; q < CHUNK / 4; ++q) xv[q] = ys[q];
            } else {
                const float4* hb = (const float4*)&h_buf[(p - 1) & 1][l - 1][0];
                #pragma unroll
                for (int q = 0; q < CHUNK / 4; ++q) xv[q] = hb[q];
            }
            float xs[CHUNK];
            #pragma unroll
            for (int q = 0; q < CHUNK / 4; ++q) {
                xs[4 * q + 0] = xv[q].x; xs[4 * q + 1] = xv[q].y;
                xs[4 * q + 2] = xv[q].z; xs[4 * q + 3] = xv[q].w;
            }

            // Input-side gate contributions: independent of h, off the chain.
            float p0[CHUNK], p1[CHUNK], p2[CHUNK], p3[CHUNK];
            #pragma unroll
            for (int j = 0; j < CHUNK; ++j) {
                p0[j] = fmaf(xs[j], wi0, bb0);
                p1[j] = fmaf(xs[j], wi1, bb1);
                p2[j] = fmaf(xs[j], wi2, bb2);
                p3[j] = fmaf(xs[j], wi3, bb3);
            }

            #pragma unroll
            for (int j = 0; j < CHUNK; ++j) {
                // Gate pre-activations (scale factors pre-folded into weights).
                const float gi = fmaf(h, wh0, p0[j]);
                const float gf = fmaf(h, wh1, p1[j]);
                const float gg = fmaf(h, wh2, p2[j]);
                const float go = fmaf(h, wh3, p3[j]);

                const float si = fast_rcp(1.0f + fast_exp2(gi));
                const float sf = fast_rcp(1.0f + fast_exp2(gf));
                const float rg = fast_rcp(1.0f + fast_exp2(gg));
                const float so = fast_rcp(1.0f + fast_exp2(go));

                // tanh(gg_orig) scaled by K2, folded into one fma.
                const float tgK = fmaf(-2.0f * K2, rg, K2);
                C = fmaf(sf, C, si * tgK);

                const float sw = so * wr;                 // off the C-chain
                const float rc = fast_rcp(1.0f + fast_exp2(C));
                const float v  = fmaf(-2.0f * sw, rc, sw); // sw * tanh(c)

                const float vs = wave_sum_lane63(v);      // lane 63 = sum

                if (k == 63) {
                    if (l < LAYERS - 1) h_buf[p & 1][l][j] = vs;  // next layer
                    else                out_lds[t0 + j]   = vs;   // final output
                }
                // Broadcast for this wave's own next step.
                h = __int_as_float(
                    __builtin_amdgcn_readlane(__float_as_int(vs), 63));
            }
        }
    }

    // Flush buffered outputs to global once (coalesced).
    __syncthreads();
    const int nout = SEQT - msl;
    float* outb = out + (size_t)b * nout;
    for (int i = tid; i < nout; i += 256) outb[i] = out_lds[i + msl];
}

extern "C" void kernel_launch(void* const* d_in, const int* in_sizes, int n_in,
                              void* d_out, int out_size, void* d_ws, size_t ws_size,
                              hipStream_t stream) {
    const float* y    = (const float*)d_in[0];
    const float* W_ih = (const float*)d_in[1];
    const float* W_hh = (const float*)d_in[2];
    const float* b_ih = (const float*)d_in[3];
    const float* b_hh = (const float*)d_in[4];
    const float* W_hr = (const float*)d_in[5];
    const int*   msl  = (const int*)d_in[6];
    float* out = (float*)d_out;

    lstm_pipeline_kernel<<<BATCH, 256, 0, stream>>>(
        y, W_ih, W_hh, b_ih, b_hh, W_hr, msl, out);
}

// Round 5
// 336.067 us; speedup vs baseline: 1.6200x; 1.0137x over previous
//
#include <hip/hip_runtime.h>

// Problem constants (fixed by the reference setup).
#define BATCH  256
#define SEQT   2048
#define LAYERS 4
#define HID    64
#define CHUNK  16                        // timesteps per barrier phase
#define PHASES (SEQT / CHUNK + LAYERS - 1)
// P (input / projected hidden size) == 1

#define LOG2E  1.4426950408889634f
#define K2     (2.0f * LOG2E)            // c is carried as C = K2 * c

__device__ __forceinline__ float fast_rcp(float x) {
    return __builtin_amdgcn_rcpf(x);
}
__device__ __forceinline__ float fast_exp2(float x) {
    return __builtin_amdgcn_exp2f(x);    // raw v_exp_f32 (2^x)
}

// One DPP-shifted add: v += dpp_move(v). bound_ctrl=true -> invalid lanes read 0.
#define DPP_ADD(v, ctrl)                                                     \
    (v) += __int_as_float(__builtin_amdgcn_update_dpp(                       \
        0, __float_as_int(v), (ctrl), 0xF, 0xF, true))

// Full wave64 sum via DPP row reduce + row broadcasts; total lands in lane 63.
__device__ __forceinline__ float wave_sum_lane63(float v) {
    DPP_ADD(v, 0x111);   // row_shr:1
    DPP_ADD(v, 0x112);   // row_shr:2
    DPP_ADD(v, 0x114);   // row_shr:4
    DPP_ADD(v, 0x118);   // row_shr:8 -> lanes 15/31/47/63 = row sums
    DPP_ADD(v, 0x142);   // row_bcast:15
    DPP_ADD(v, 0x143);   // row_bcast:31 -> lane 63 = full sum
    return v;
}

// One block per batch element. 4 waves = 4 layers, software-pipelined across
// time in CHUNK-step phases: wave l in phase p handles t in [C*(p-l), +C).
// Inter-layer h flows through double-buffered LDS once per phase; outputs are
// LDS-buffered and flushed once (keeps vmcnt off the per-phase barriers).
// exp() scale factors are pre-folded into weights; cell state carried as
// C = 2*log2e*c. Per step only 8 transcendentals: 5 exp2 + 3 rcp --
// sigmoid*tanh pairs share one reciprocal:
//   si*tanh(g)*K2 = K2(Eg-1) * rcp((1+Ei)(1+Eg)),  Ei=e^-i, Eg=e^{2g}
//   so*tanh(c)*wr = wr(Ec-1) * rcp((1+Eo)(1+Ec)),  Eo=e^-o, Ec=e^{2c}
__global__ __launch_bounds__(256, 1) void lstm_pipeline_kernel(
    const float* __restrict__ y,      // [B, T, 1]
    const float* __restrict__ W_ih,   // [L, 4H, 1]
    const float* __restrict__ W_hh,   // [L, 4H, 1]
    const float* __restrict__ b_ih,   // [L, 4H]
    const float* __restrict__ b_hh,   // [L, 4H]
    const float* __restrict__ W_hr,   // [L, 1, H]
    const int*  __restrict__ msl_p,   // min_seq_len scalar
    float* __restrict__ out)          // [B, T - msl, 1]
{
    const int b   = blockIdx.x;
    const int tid = threadIdx.x;
    const int l   = tid >> 6;   // layer / wave id
    const int k   = tid & 63;   // hidden unit / lane
    const int msl = *msl_p;

    __shared__ float y_lds[SEQT];                              // 8 KB
    __shared__ float out_lds[SEQT];                            // 8 KB
    __shared__ __align__(16) float h_buf[2][LAYERS][CHUNK];    // inter-layer h

    // Stage y[b, :] into LDS with float4 loads.
    {
        const float4* y4  = (const float4*)(y + (size_t)b * SEQT);
        float4*       yl4 = (float4*)y_lds;
        #pragma unroll
        for (int i = tid; i < SEQT / 4; i += 256) yl4[i] = y4[i];
    }

    // Loop-invariant weights. Gate order: i, f, g, o.
    // i, f, o carry -log2e (so exp2 gives e^-gate); g carries 2*log2e.
    const int wbase = l * 4 * HID;
    const float wi0 = -LOG2E * W_ih[wbase + 0 * HID + k];
    const float wi1 = -LOG2E * W_ih[wbase + 1 * HID + k];
    const float wi2 =  K2    * W_ih[wbase + 2 * HID + k];
    const float wi3 = -LOG2E * W_ih[wbase + 3 * HID + k];
    const float wh0 = -LOG2E * W_hh[wbase + 0 * HID + k];
    const float wh1 = -LOG2E * W_hh[wbase + 1 * HID + k];
    const float wh2 =  K2    * W_hh[wbase + 2 * HID + k];
    const float wh3 = -LOG2E * W_hh[wbase + 3 * HID + k];
    const float bb0 = -LOG2E * (b_ih[wbase + 0 * HID + k] + b_hh[wbase + 0 * HID + k]);
    const float bb1 = -LOG2E * (b_ih[wbase + 1 * HID + k] + b_hh[wbase + 1 * HID + k]);
    const float bb2 =  K2    * (b_ih[wbase + 2 * HID + k] + b_hh[wbase + 2 * HID + k]);
    const float bb3 = -LOG2E * (b_ih[wbase + 3 * HID + k] + b_hh[wbase + 3 * HID + k]);
    const float wr  = W_hr[l * HID + k];

    float h = 0.0f;   // projected hidden (wave-uniform)
    float C = 0.0f;   // cell state, scaled: C = 2*log2e*c

    for (int p = 0; p < PHASES; ++p) {
        __syncthreads();   // publishes previous phase's h_buf writes (LDS only)
        const int t0 = (p - l) * CHUNK;
        if (t0 >= 0 && t0 < SEQT) {
            // Fetch this chunk's 16 scalar inputs (wave-uniform broadcast reads).
            float4 xv[CHUNK / 4];
            if (l == 0) {
                const float4* ys = (const float4*)&y_lds[t0];
                #pragma unroll
                for (int q = 0; q < CHUNK / 4; ++q) xv[q] = ys[q];
            } else {
                const float4* hb = (const float4*)&h_buf[(p - 1) & 1][l - 1][0];
                #pragma unroll
                for (int q = 0; q < CHUNK / 4; ++q) xv[q] = hb[q];
            }
            float xs[CHUNK];
            #pragma unroll
            for (int q = 0; q < CHUNK / 4; ++q) {
                xs[4 * q + 0] = xv[q].x; xs[4 * q + 1] = xv[q].y;
                xs[4 * q + 2] = xv[q].z; xs[4 * q + 3] = xv[q].w;
            }

            // Input-side gate contributions: independent of h, off the chain.
            float p0[CHUNK], p1[CHUNK], p2[CHUNK], p3[CHUNK];
            #pragma unroll
            for (int j = 0; j < CHUNK; ++j) {
                p0[j] = fmaf(xs[j], wi0, bb0);
                p1[j] = fmaf(xs[j], wi1, bb1);
                p2[j] = fmaf(xs[j], wi2, bb2);
                p3[j] = fmaf(xs[j], wi3, bb3);
            }

            #pragma unroll
            for (int j = 0; j < CHUNK; ++j) {
                // Gate pre-activations (scale factors pre-folded into weights).
                const float gi = fmaf(h, wh0, p0[j]);
                const float gf = fmaf(h, wh1, p1[j]);
                const float gg = fmaf(h, wh2, p2[j]);
                const float go = fmaf(h, wh3, p3[j]);

                const float Ei = fast_exp2(gi);     // e^-i
                const float Ef = fast_exp2(gf);     // e^-f
                const float Eg = fast_exp2(gg);     // e^{2g}
                const float Eo = fast_exp2(go);     // e^-o

                // sf = sigmoid(f)
                const float sf = fast_rcp(1.0f + Ef);

                // si * tanh(g) * K2, single reciprocal.
                const float num_g  = fmaf(K2, Eg, -K2);             // K2(Eg-1)
                const float den_ig = (1.0f + Ei) * (1.0f + Eg);
                const float si_tgK = num_g * fast_rcp(den_ig);

                C = fmaf(sf, C, si_tgK);

                // v = so * tanh(c) * wr, single reciprocal.
                const float Ec     = fast_exp2(C);                  // e^{2c}
                const float num_o  = fmaf(wr, Ec, -wr);             // wr(Ec-1)
                const float den_oc = (1.0f + Eo) * (1.0f + Ec);
                const float v      = num_o * fast_rcp(den_oc);

                const float vs = wave_sum_lane63(v);      // lane 63 = sum

                if (k == 63) {
                    if (l < LAYERS - 1) h_buf[p & 1][l][j] = vs;  // next layer
                    else                out_lds[t0 + j]   = vs;   // final output
                }
                // Broadcast for this wave's own next step.
                h = __int_as_float(
                    __builtin_amdgcn_readlane(__float_as_int(vs), 63));
            }
        }
    }

    // Flush buffered outputs to global once (coalesced).
    __syncthreads();
    const int nout = SEQT - msl;
    float* outb = out + (size_t)b * nout;
    for (int i = tid; i < nout; i += 256) outb[i] = out_lds[i + msl];
}

extern "C" void kernel_launch(void* const* d_in, const int* in_sizes, int n_in,
                              void* d_out, int out_size, void* d_ws, size_t ws_size,
                              hipStream_t stream) {
    const float* y    = (const float*)d_in[0];
    const float* W_ih = (const float*)d_in[1];
    const float* W_hh = (const float*)d_in[2];
    const float* b_ih = (const float*)d_in[3];
    const float* b_hh = (const float*)d_in[4];
    const float* W_hr = (const float*)d_in[5];
    const int*   msl  = (const int*)d_in[6];
    float* out = (float*)d_out;

    lstm_pipeline_kernel<<<BATCH, 256, 0, stream>>>(
        y, W_ih, W_hh, b_ih, b_hh, W_hr, msl, out);
}